// Round 5
// baseline (103.609 us; speedup 1.0000x reference)
//
#include <hip/hip_runtime.h>
#include <hip/hip_bf16.h>

// F=128, H=128, K=768, T=4, IT=2, S=57
// Factorizations:
//  elat[i,j,:] = relu(A[i]+B[j]+b_lat), A = cf@Wel[:128], B = cf@Wel[128:]
//  new_cf[i,h] = relu(A0[i,h]+b_ne[h]+ max_{j: emask[i,j]} B0[j,h])

#define NK 768
#define NH 128
#define NCF 98304   // 768*128

typedef float v2f __attribute__((ext_vector_type(2)));

// K1: cf0 = relu(pf @ Wp + bp); exists = cf0 @ Wexi + bexi; flag = 0
__global__ __launch_bounds__(256) void k_parent(const float* __restrict__ pf,
    const float* __restrict__ Wp, const float* __restrict__ bp,
    const float* __restrict__ Wexi, const float* __restrict__ bexi,
    float* __restrict__ cf0, float* __restrict__ exO, unsigned int* __restrict__ flag)
{
    __shared__ float s_pf[128];
    __shared__ float4 s_part[8][32];
    int t = threadIdx.x;
    if (t < 128) s_pf[t] = pf[t];
    if (blockIdx.x == 0 && t == 0) *flag = 0u;
    __syncthreads();
    int c = t & 31, g = t >> 5;
    int col4 = blockIdx.x * 32 + c;             // float4-column
    const float4* W4 = (const float4*)Wp;       // row stride 24576 float4
    float4 acc = make_float4(0.f, 0.f, 0.f, 0.f);
    #pragma unroll
    for (int q = 0; q < 16; ++q) {
        int f = g * 16 + q;
        float4 w = W4[(size_t)f * 24576 + col4];
        float p = s_pf[f];
        acc.x = fmaf(p, w.x, acc.x);
        acc.y = fmaf(p, w.y, acc.y);
        acc.z = fmaf(p, w.z, acc.z);
        acc.w = fmaf(p, w.w, acc.w);
    }
    s_part[g][c] = acc;
    __syncthreads();
    if (t < 32) {
        float4 r = s_part[0][t];
        #pragma unroll
        for (int q = 1; q < 8; ++q) {
            float4 p = s_part[q][t];
            r.x += p.x; r.y += p.y; r.z += p.z; r.w += p.w;
        }
        float4 bi = ((const float4*)bp)[col4];
        r.x = fmaxf(r.x + bi.x, 0.f);
        r.y = fmaxf(r.y + bi.y, 0.f);
        r.z = fmaxf(r.z + bi.z, 0.f);
        r.w = fmaxf(r.w + bi.w, 0.f);
        ((float4*)cf0)[col4] = r;
        float4 w = ((const float4*)Wexi)[t];
        float dot = r.x * w.x + r.y * w.y + r.z * w.z + r.w * w.w;
        dot += __shfl_xor(dot, 16);
        dot += __shfl_xor(dot, 8);
        dot += __shfl_xor(dot, 4);
        dot += __shfl_xor(dot, 2);
        dot += __shfl_xor(dot, 1);
        if (t == 0) exO[blockIdx.x] = dot + bexi[0];
    }
}

// K2: dual 768x128 @ 128x128x2 GEMM. grid(192,2) x 512 thr.
__global__ __launch_bounds__(512) void k_dualmm(const float* __restrict__ src,
    const float* __restrict__ Wel, float* __restrict__ A, float* __restrict__ BT,
    const float* __restrict__ Wne, float* __restrict__ A0, float* __restrict__ B0)
{
    __shared__ float s_cf[4][128];
    __shared__ float s_bt[128][4];
    int t = threadIdx.x;
    int k0 = blockIdx.x * 4;
    int set = blockIdx.y;
    s_cf[t >> 7][t & 127] = src[k0 * 128 + t];
    __syncthreads();
    int h = t & 127, sub = (t >> 7) & 1, half = t >> 8;
    const float* W = (set ? Wne : Wel) + half * 16384;
    const float* c0 = &s_cf[sub * 2][0];
    const float* c1 = &s_cf[sub * 2 + 1][0];
    float a0 = 0.f, a1 = 0.f;
    #pragma unroll 8
    for (int r = 0; r < 128; ++r) {
        float w = W[r * 128 + h];
        a0 = fmaf(c0[r], w, a0);
        a1 = fmaf(c1[r], w, a1);
    }
    if (half == 0) {
        float* D = set ? A0 : A;
        D[(k0 + sub * 2) * 128 + h] = a0;
        D[(k0 + sub * 2 + 1) * 128 + h] = a1;
    } else if (set) {
        B0[(k0 + sub * 2) * 128 + h] = a0;
        B0[(k0 + sub * 2 + 1) * 128 + h] = a1;
    } else {
        s_bt[h][sub * 2] = a0;
        s_bt[h][sub * 2 + 1] = a1;
    }
    __syncthreads();
    if (set == 0 && t < 128)
        *(float4*)(BT + (size_t)t * NK + k0) = *(const float4*)&s_bt[t][0];
}

// K3: edge logits + emask + any_edge. grid(192,3) x 256, tile 4i x 256j.
// LDS-staged BT double-buffered; packed-f32 inner loop (i-pairs in v2f).
__global__ __launch_bounds__(256) void k_edge(const float* __restrict__ A,
    const float* __restrict__ BT, const float* __restrict__ b_lat,
    const float* __restrict__ Wex, const float* __restrict__ bex,
    const float* __restrict__ exO, float* __restrict__ edge_out,
    unsigned char* __restrict__ mask, unsigned int* __restrict__ flag)
{
    __shared__ float4 s_A[128];         // A[i0..i0+3][h] + b_lat[h]
    __shared__ float4 s_W[128];         // Wex[0..3][h]
    __shared__ float s_B[2][16][256];   // BT chunk, double-buffered
    __shared__ float s_exi[4];
    __shared__ unsigned int s_any;
    int t = threadIdx.x;
    int i0 = blockIdx.x * 4;
    int j = blockIdx.y * 256 + t;
    float exj = exO[j];                 // issue early
    if (t < 128) {
        float bl = b_lat[t];
        s_A[t] = make_float4(A[(i0 + 0) * 128 + t] + bl, A[(i0 + 1) * 128 + t] + bl,
                             A[(i0 + 2) * 128 + t] + bl, A[(i0 + 3) * 128 + t] + bl);
        s_W[t] = make_float4(Wex[t], Wex[128 + t], Wex[256 + t], Wex[384 + t]);
    }
    if (t < 4) s_exi[t] = exO[i0 + t];
    if (t == 0) s_any = 0u;
    const float4* BT4 = (const float4*)BT;      // row stride 192 float4
    int row = t >> 6, col = t & 63;
    {
        #pragma unroll
        for (int k = 0; k < 4; ++k)
            *(float4*)&s_B[0][row + k * 4][col * 4] =
                BT4[(size_t)(row + k * 4) * 192 + blockIdx.y * 64 + col];
    }
    __syncthreads();
    v2f l01[4] = {}, l23[4] = {};
    for (int c = 0; c < 8; ++c) {
        float4 r0, r1, r2, r3;
        if (c < 7) {
            size_t base = (size_t)((c + 1) * 16 + row) * 192 + blockIdx.y * 64 + col;
            r0 = BT4[base];
            r1 = BT4[base + 4 * 192];
            r2 = BT4[base + 8 * 192];
            r3 = BT4[base + 12 * 192];
        }
        int buf = c & 1;
        #pragma unroll
        for (int hh = 0; hh < 16; ++hh) {
            float bv = s_B[buf][hh][t];
            float4 av = s_A[c * 16 + hh];
            float4 wv = s_W[c * 16 + hh];
            v2f e01 = __builtin_elementwise_max((v2f){av.x + bv, av.y + bv}, (v2f){0.f, 0.f});
            v2f e23 = __builtin_elementwise_max((v2f){av.z + bv, av.w + bv}, (v2f){0.f, 0.f});
            l01[0] += e01 * wv.x; l01[1] += e01 * wv.y;
            l01[2] += e01 * wv.z; l01[3] += e01 * wv.w;
            l23[0] += e23 * wv.x; l23[1] += e23 * wv.y;
            l23[2] += e23 * wv.z; l23[3] += e23 * wv.w;
        }
        if (c < 7) {
            int nb = (c + 1) & 1;
            *(float4*)&s_B[nb][row + 0][col * 4] = r0;
            *(float4*)&s_B[nb][row + 4][col * 4] = r1;
            *(float4*)&s_B[nb][row + 8][col * 4] = r2;
            *(float4*)&s_B[nb][row + 12][col * 4] = r3;
        }
        __syncthreads();
    }
    float b0 = bex[0], b1 = bex[1], b2 = bex[2], b3 = bex[3];
    bool ej = exj > 0.f;
    float4 v0 = make_float4(l01[0].x + b0, l01[1].x + b1, l01[2].x + b2, l01[3].x + b3);
    float4 v1 = make_float4(l01[0].y + b0, l01[1].y + b1, l01[2].y + b2, l01[3].y + b3);
    float4 v2 = make_float4(l23[0].x + b0, l23[1].x + b1, l23[2].x + b2, l23[3].x + b3);
    float4 v3 = make_float4(l23[0].y + b0, l23[1].y + b1, l23[2].y + b2, l23[3].y + b3);
    ((float4*)edge_out)[(size_t)(i0 + 0) * NK + j] = v0;
    ((float4*)edge_out)[(size_t)(i0 + 1) * NK + j] = v1;
    ((float4*)edge_out)[(size_t)(i0 + 2) * NK + j] = v2;
    ((float4*)edge_out)[(size_t)(i0 + 3) * NK + j] = v3;
    bool m0 = ((v0.x > 0.f) | (v0.y > 0.f) | (v0.z > 0.f) | (v0.w > 0.f)) && ej && (s_exi[0] > 0.f);
    bool m1 = ((v1.x > 0.f) | (v1.y > 0.f) | (v1.z > 0.f) | (v1.w > 0.f)) && ej && (s_exi[1] > 0.f);
    bool m2 = ((v2.x > 0.f) | (v2.y > 0.f) | (v2.z > 0.f) | (v2.w > 0.f)) && ej && (s_exi[2] > 0.f);
    bool m3 = ((v3.x > 0.f) | (v3.y > 0.f) | (v3.z > 0.f) | (v3.w > 0.f)) && ej && (s_exi[3] > 0.f);
    mask[(i0 + 0) * NK + j] = m0 ? (unsigned char)1 : (unsigned char)0;
    mask[(i0 + 1) * NK + j] = m1 ? (unsigned char)1 : (unsigned char)0;
    mask[(i0 + 2) * NK + j] = m2 ? (unsigned char)1 : (unsigned char)0;
    mask[(i0 + 3) * NK + j] = m3 ? (unsigned char)1 : (unsigned char)0;
    unsigned long long bal = __ballot((m0 | m1 | m2 | m3) ? 1 : 0);
    if ((t & 63) == 0 && bal) s_any = 1u;
    __syncthreads();
    if (t == 0 && s_any) *flag = 1u;    // idempotent plain store
}

// K4: fused masked-max over ALL j + combine -> cf1 + GEMM Wne1 -> A1,B1.
// grid 384 x 256, i-tile 2, j split in 2 halves across t>>7.
__global__ __launch_bounds__(256) void k_msg1(const float* __restrict__ B0m,
    const unsigned char* __restrict__ mask, const float* __restrict__ A0,
    const float* __restrict__ bne, const float* __restrict__ cf0,
    const unsigned int* __restrict__ flag, float* __restrict__ cf1,
    const float* __restrict__ Wne1, float* __restrict__ A1, float* __restrict__ B1)
{
    __shared__ float s_madd[768][2];
    __shared__ float s_red[2][256];
    __shared__ float s_cf[2][128];
    int t = threadIdx.x;
    int i0 = blockIdx.x * 2;
    for (int idx = t; idx < 1536; idx += 256) {
        int i = idx & 1, jj = idx >> 1;
        s_madd[jj][i] = mask[(i0 + i) * NK + jj] ? 0.f : -1e30f;
    }
    __syncthreads();
    int h = t & 127, s = t >> 7;
    float M0 = -1e30f, M1 = -1e30f;
    const float* bp2 = B0m + (size_t)(s * 384) * 128 + h;
    #pragma unroll 8
    for (int jj = 0; jj < 384; ++jj) {
        float bv = bp2[(size_t)jj * 128];
        float2 m = *(const float2*)&s_madd[s * 384 + jj][0];
        M0 = fmaxf(M0, bv + m.x);
        M1 = fmaxf(M1, bv + m.y);
    }
    s_red[0][t] = M0;
    s_red[1][t] = M1;
    __syncthreads();
    unsigned int fl = *flag;
    if (s == 0) {
        M0 = fmaxf(M0, s_red[0][128 + h]);
        M1 = fmaxf(M1, s_red[1][128 + h]);
        int g0 = i0 * 128 + h, g1 = (i0 + 1) * 128 + h;
        float bh = bne[h];
        float v0 = fl ? fmaxf(A0[g0] + bh + M0, 0.f) : cf0[g0];
        float v1 = fl ? fmaxf(A0[g1] + bh + M1, 0.f) : cf0[g1];
        s_cf[0][h] = v0; s_cf[1][h] = v1;
        cf1[g0] = v0; cf1[g1] = v1;
    }
    __syncthreads();
    const float* W = Wne1 + s * 16384;
    const float* c0 = &s_cf[0][0];
    const float* c1 = &s_cf[1][0];
    float a0 = 0.f, a1 = 0.f;
    #pragma unroll 8
    for (int r = 0; r < 128; ++r) {
        float w = W[r * 128 + h];
        a0 = fmaf(c0[r], w, a0);
        a1 = fmaf(c1[r], w, a1);
    }
    float* D = s ? B1 : A1;
    D[i0 * 128 + h] = a0;
    D[(i0 + 1) * 128 + h] = a1;
}

// K5: fused masked-max (B1) + combine -> cf2 (local) + final heads.
// grid 384 x 256, i-tile 2.
__global__ __launch_bounds__(256) void k_msg2(const float* __restrict__ B1m,
    const unsigned char* __restrict__ mask, const float* __restrict__ A1,
    const float* __restrict__ bne1, const float* __restrict__ cf0,
    const float* __restrict__ cf1, const unsigned int* __restrict__ flag,
    const float* __restrict__ Wc, const float* __restrict__ bc,
    const float* __restrict__ Wsem, const float* __restrict__ bsem,
    const float* __restrict__ W2, const float* __restrict__ b2,
    float* __restrict__ out)
{
    __shared__ float s_madd[768][2];
    __shared__ float s_red[2][256];
    __shared__ float s_f[2][384];
    __shared__ float s_h[2][128];
    int t = threadIdx.x;
    int i0 = blockIdx.x * 2;
    for (int idx = t; idx < 1536; idx += 256) {
        int i = idx & 1, jj = idx >> 1;
        s_madd[jj][i] = mask[(i0 + i) * NK + jj] ? 0.f : -1e30f;
    }
    __syncthreads();
    int h = t & 127, s = t >> 7;
    float M0 = -1e30f, M1 = -1e30f;
    const float* bp2 = B1m + (size_t)(s * 384) * 128 + h;
    #pragma unroll 8
    for (int jj = 0; jj < 384; ++jj) {
        float bv = bp2[(size_t)jj * 128];
        float2 m = *(const float2*)&s_madd[s * 384 + jj][0];
        M0 = fmaxf(M0, bv + m.x);
        M1 = fmaxf(M1, bv + m.y);
    }
    s_red[0][t] = M0;
    s_red[1][t] = M1;
    __syncthreads();
    unsigned int fl = *flag;
    int g0 = i0 * 128 + h, g1 = (i0 + 1) * 128 + h;
    if (s == 0) {
        M0 = fmaxf(M0, s_red[0][128 + h]);
        M1 = fmaxf(M1, s_red[1][128 + h]);
        float bh = bne1[h];
        float f10 = cf1[g0], f11 = cf1[g1];
        s_f[0][256 + h] = fl ? fmaxf(A1[g0] + bh + M0, 0.f) : f10;
        s_f[1][256 + h] = fl ? fmaxf(A1[g1] + bh + M1, 0.f) : f11;
        s_f[0][128 + h] = f10;
        s_f[1][128 + h] = f11;
    } else {
        s_f[0][h] = cf0[g0];
        s_f[1][h] = cf0[g1];
    }
    __syncthreads();
    int kg = s;
    float acc = 0.f;
    {
        const float* f = &s_f[kg][0];
        #pragma unroll 8
        for (int r = 0; r < 384; ++r)
            acc = fmaf(f[r], Wc[r * 128 + h], acc);
    }
    s_h[kg][h] = fmaxf(acc + bc[h], 0.f);
    __syncthreads();
    float a2 = 0.f;
    {
        const float* hr = &s_h[kg][0];
        #pragma unroll 8
        for (int r = 0; r < 128; ++r)
            a2 = fmaf(hr[r], W2[r * 128 + h], a2);
    }
    out[(size_t)(i0 + kg) * 128 + h] = fmaxf(a2 + b2[h], 0.f);
    if (t < 114) {
        int kk = t / 57, sidx = t - kk * 57;
        float ss = bsem[sidx];
        const float* hr = &s_h[kk][0];
        #pragma unroll 8
        for (int r = 0; r < 128; ++r)
            ss = fmaf(hr[r], Wsem[r * 57 + sidx], ss);
        out[98304 + (size_t)(i0 + kk) * 57 + sidx] = ss;
    }
}

extern "C" void kernel_launch(void* const* d_in, const int* in_sizes, int n_in,
                              void* d_out, int out_size, void* d_ws, size_t ws_size,
                              hipStream_t stream) {
    const float* pf   = (const float*)d_in[0];
    const float* Wp   = (const float*)d_in[1];
    const float* bp   = (const float*)d_in[2];
    const float* Wexi = (const float*)d_in[3];
    const float* bexi = (const float*)d_in[4];
    const float* Wel  = (const float*)d_in[5];
    const float* bel  = (const float*)d_in[6];
    const float* Wee  = (const float*)d_in[7];
    const float* bee  = (const float*)d_in[8];
    const float* Wne  = (const float*)d_in[9];
    const float* bne  = (const float*)d_in[10];
    const float* Wc   = (const float*)d_in[11];
    const float* bc   = (const float*)d_in[12];
    const float* Wsem = (const float*)d_in[13];
    const float* bsem = (const float*)d_in[14];
    const float* W2   = (const float*)d_in[15];
    const float* b2   = (const float*)d_in[16];
    float* out = (float*)d_out;
    float* ws  = (float*)d_ws;
    const int N = NCF;
    float* cf0 = ws;
    float* cf1 = ws + N;
    float* A   = ws + 2 * N;
    float* BT  = ws + 3 * N;
    float* A0  = ws + 4 * N;
    float* B0  = ws + 5 * N;
    float* A1  = ws + 6 * N;
    float* B1  = ws + 7 * N;
    unsigned char* mask = (unsigned char*)(ws + 8 * N);    // 589824 bytes
    unsigned int* flag  = (unsigned int*)(mask + 589824);

    float* out_ex   = out + 142080;
    float* out_edge = out + 142848;

    k_parent<<<768, 256, 0, stream>>>(pf, Wp, bp, Wexi, bexi, cf0, out_ex, flag);
    k_dualmm<<<dim3(192, 2), 512, 0, stream>>>(cf0, Wel, A, BT, Wne, A0, B0);
    k_edge<<<dim3(192, 3), 256, 0, stream>>>(A, BT, bel, Wee, bee, out_ex, out_edge, mask, flag);
    k_msg1<<<384, 256, 0, stream>>>(B0, mask, A0, bne, cf0, flag, cf1, Wne + 32768, A1, B1);
    k_msg2<<<384, 256, 0, stream>>>(B1, mask, A1, bne + 128, cf0, cf1, flag,
                                    Wc, bc, Wsem, bsem, W2, b2, out);
}

// Round 6
// 83.448 us; speedup vs baseline: 1.2416x; 1.2416x over previous
//
#include <hip/hip_runtime.h>
#include <hip/hip_bf16.h>

// F=128, H=128, K=768, T=4, IT=2, S=57
// Factorizations:
//  elat[i,j,:] = relu(A[i]+B[j]+b_lat), A = cf@Wel[:128], B = cf@Wel[128:]
//  new_cf[i,h] = relu(A0[i,h]+b_ne[h]+ max_{j: emask[i,j]} B0[j,h])
//  masked max as max-plus GEMM: M[i,h] = max_j (B[j,h] + madd[i,j])

#define NK 768
#define NH 128
#define NCF 98304   // 768*128

typedef float v2f __attribute__((ext_vector_type(2)));

// K1: cf0 = relu(pf @ Wp + bp); exists = cf0 @ Wexi + bexi; flag = 0
__global__ __launch_bounds__(256) void k_parent(const float* __restrict__ pf,
    const float* __restrict__ Wp, const float* __restrict__ bp,
    const float* __restrict__ Wexi, const float* __restrict__ bexi,
    float* __restrict__ cf0, float* __restrict__ exO, unsigned int* __restrict__ flag)
{
    __shared__ float s_pf[128];
    __shared__ float4 s_part[8][32];
    int t = threadIdx.x;
    if (t < 128) s_pf[t] = pf[t];
    if (blockIdx.x == 0 && t == 0) *flag = 0u;
    __syncthreads();
    int c = t & 31, g = t >> 5;
    int col4 = blockIdx.x * 32 + c;             // float4-column
    const float4* W4 = (const float4*)Wp;       // row stride 24576 float4
    float4 acc = make_float4(0.f, 0.f, 0.f, 0.f);
    #pragma unroll
    for (int q = 0; q < 16; ++q) {
        int f = g * 16 + q;
        float4 w = W4[(size_t)f * 24576 + col4];
        float p = s_pf[f];
        acc.x = fmaf(p, w.x, acc.x);
        acc.y = fmaf(p, w.y, acc.y);
        acc.z = fmaf(p, w.z, acc.z);
        acc.w = fmaf(p, w.w, acc.w);
    }
    s_part[g][c] = acc;
    __syncthreads();
    if (t < 32) {
        float4 r = s_part[0][t];
        #pragma unroll
        for (int q = 1; q < 8; ++q) {
            float4 p = s_part[q][t];
            r.x += p.x; r.y += p.y; r.z += p.z; r.w += p.w;
        }
        float4 bi = ((const float4*)bp)[col4];
        r.x = fmaxf(r.x + bi.x, 0.f);
        r.y = fmaxf(r.y + bi.y, 0.f);
        r.z = fmaxf(r.z + bi.z, 0.f);
        r.w = fmaxf(r.w + bi.w, 0.f);
        ((float4*)cf0)[col4] = r;
        float4 w = ((const float4*)Wexi)[t];
        float dot = r.x * w.x + r.y * w.y + r.z * w.z + r.w * w.w;
        dot += __shfl_xor(dot, 16);
        dot += __shfl_xor(dot, 8);
        dot += __shfl_xor(dot, 4);
        dot += __shfl_xor(dot, 2);
        dot += __shfl_xor(dot, 1);
        if (t == 0) exO[blockIdx.x] = dot + bexi[0];
    }
}

// K2: dual 768x128 @ 128x128x2 GEMM. grid(192,2) x 512 thr.
__global__ __launch_bounds__(512) void k_dualmm(const float* __restrict__ src,
    const float* __restrict__ Wel, float* __restrict__ A, float* __restrict__ BT,
    const float* __restrict__ Wne, float* __restrict__ A0, float* __restrict__ B0)
{
    __shared__ float s_cf[4][128];
    __shared__ float s_bt[128][4];
    int t = threadIdx.x;
    int k0 = blockIdx.x * 4;
    int set = blockIdx.y;
    s_cf[t >> 7][t & 127] = src[k0 * 128 + t];
    __syncthreads();
    int h = t & 127, sub = (t >> 7) & 1, half = t >> 8;
    const float* W = (set ? Wne : Wel) + half * 16384;
    const float* c0 = &s_cf[sub * 2][0];
    const float* c1 = &s_cf[sub * 2 + 1][0];
    float a0 = 0.f, a1 = 0.f;
    #pragma unroll 8
    for (int r = 0; r < 128; ++r) {
        float w = W[r * 128 + h];
        a0 = fmaf(c0[r], w, a0);
        a1 = fmaf(c1[r], w, a1);
    }
    if (half == 0) {
        float* D = set ? A0 : A;
        D[(k0 + sub * 2) * 128 + h] = a0;
        D[(k0 + sub * 2 + 1) * 128 + h] = a1;
    } else if (set) {
        B0[(k0 + sub * 2) * 128 + h] = a0;
        B0[(k0 + sub * 2 + 1) * 128 + h] = a1;
    } else {
        s_bt[h][sub * 2] = a0;
        s_bt[h][sub * 2 + 1] = a1;
    }
    __syncthreads();
    if (set == 0 && t < 128)
        *(float4*)(BT + (size_t)t * NK + k0) = *(const float4*)&s_bt[t][0];
}

// K3: edge logits + emask + any_edge. grid(192,3) x 256, tile 4i x 256j.
__global__ __launch_bounds__(256) void k_edge(const float* __restrict__ A,
    const float* __restrict__ BT, const float* __restrict__ b_lat,
    const float* __restrict__ Wex, const float* __restrict__ bex,
    const float* __restrict__ exO, float* __restrict__ edge_out,
    unsigned char* __restrict__ mask, unsigned int* __restrict__ flag)
{
    __shared__ float4 s_A[128];         // A[i0..i0+3][h] + b_lat[h]
    __shared__ float4 s_W[128];         // Wex[0..3][h]
    __shared__ float s_B[2][16][256];   // BT chunk, double-buffered
    __shared__ float s_exi[4];
    __shared__ unsigned int s_any;
    int t = threadIdx.x;
    int i0 = blockIdx.x * 4;
    int j = blockIdx.y * 256 + t;
    float exj = exO[j];                 // issue early
    if (t < 128) {
        float bl = b_lat[t];
        s_A[t] = make_float4(A[(i0 + 0) * 128 + t] + bl, A[(i0 + 1) * 128 + t] + bl,
                             A[(i0 + 2) * 128 + t] + bl, A[(i0 + 3) * 128 + t] + bl);
        s_W[t] = make_float4(Wex[t], Wex[128 + t], Wex[256 + t], Wex[384 + t]);
    }
    if (t < 4) s_exi[t] = exO[i0 + t];
    if (t == 0) s_any = 0u;
    const float4* BT4 = (const float4*)BT;      // row stride 192 float4
    int row = t >> 6, col = t & 63;
    {
        #pragma unroll
        for (int k = 0; k < 4; ++k)
            *(float4*)&s_B[0][row + k * 4][col * 4] =
                BT4[(size_t)(row + k * 4) * 192 + blockIdx.y * 64 + col];
    }
    __syncthreads();
    v2f l01[4] = {}, l23[4] = {};
    for (int c = 0; c < 8; ++c) {
        float4 r0, r1, r2, r3;
        if (c < 7) {
            size_t base = (size_t)((c + 1) * 16 + row) * 192 + blockIdx.y * 64 + col;
            r0 = BT4[base];
            r1 = BT4[base + 4 * 192];
            r2 = BT4[base + 8 * 192];
            r3 = BT4[base + 12 * 192];
        }
        int buf = c & 1;
        #pragma unroll
        for (int hh = 0; hh < 16; ++hh) {
            float bv = s_B[buf][hh][t];
            float4 av = s_A[c * 16 + hh];
            float4 wv = s_W[c * 16 + hh];
            v2f e01 = __builtin_elementwise_max((v2f){av.x + bv, av.y + bv}, (v2f){0.f, 0.f});
            v2f e23 = __builtin_elementwise_max((v2f){av.z + bv, av.w + bv}, (v2f){0.f, 0.f});
            l01[0] += e01 * wv.x; l01[1] += e01 * wv.y;
            l01[2] += e01 * wv.z; l01[3] += e01 * wv.w;
            l23[0] += e23 * wv.x; l23[1] += e23 * wv.y;
            l23[2] += e23 * wv.z; l23[3] += e23 * wv.w;
        }
        if (c < 7) {
            int nb = (c + 1) & 1;
            *(float4*)&s_B[nb][row + 0][col * 4] = r0;
            *(float4*)&s_B[nb][row + 4][col * 4] = r1;
            *(float4*)&s_B[nb][row + 8][col * 4] = r2;
            *(float4*)&s_B[nb][row + 12][col * 4] = r3;
        }
        __syncthreads();
    }
    float b0 = bex[0], b1 = bex[1], b2 = bex[2], b3 = bex[3];
    bool ej = exj > 0.f;
    float4 v0 = make_float4(l01[0].x + b0, l01[1].x + b1, l01[2].x + b2, l01[3].x + b3);
    float4 v1 = make_float4(l01[0].y + b0, l01[1].y + b1, l01[2].y + b2, l01[3].y + b3);
    float4 v2 = make_float4(l23[0].x + b0, l23[1].x + b1, l23[2].x + b2, l23[3].x + b3);
    float4 v3 = make_float4(l23[0].y + b0, l23[1].y + b1, l23[2].y + b2, l23[3].y + b3);
    ((float4*)edge_out)[(size_t)(i0 + 0) * NK + j] = v0;
    ((float4*)edge_out)[(size_t)(i0 + 1) * NK + j] = v1;
    ((float4*)edge_out)[(size_t)(i0 + 2) * NK + j] = v2;
    ((float4*)edge_out)[(size_t)(i0 + 3) * NK + j] = v3;
    bool m0 = ((v0.x > 0.f) | (v0.y > 0.f) | (v0.z > 0.f) | (v0.w > 0.f)) && ej && (s_exi[0] > 0.f);
    bool m1 = ((v1.x > 0.f) | (v1.y > 0.f) | (v1.z > 0.f) | (v1.w > 0.f)) && ej && (s_exi[1] > 0.f);
    bool m2 = ((v2.x > 0.f) | (v2.y > 0.f) | (v2.z > 0.f) | (v2.w > 0.f)) && ej && (s_exi[2] > 0.f);
    bool m3 = ((v3.x > 0.f) | (v3.y > 0.f) | (v3.z > 0.f) | (v3.w > 0.f)) && ej && (s_exi[3] > 0.f);
    mask[(i0 + 0) * NK + j] = m0 ? (unsigned char)1 : (unsigned char)0;
    mask[(i0 + 1) * NK + j] = m1 ? (unsigned char)1 : (unsigned char)0;
    mask[(i0 + 2) * NK + j] = m2 ? (unsigned char)1 : (unsigned char)0;
    mask[(i0 + 3) * NK + j] = m3 ? (unsigned char)1 : (unsigned char)0;
    unsigned long long bal = __ballot((m0 | m1 | m2 | m3) ? 1 : 0);
    if ((t & 63) == 0 && bal) s_any = 1u;
    __syncthreads();
    if (t == 0 && s_any) *flag = 1u;    // idempotent plain store
}

// K4: max-plus GEMM partials. grid(96,8) x 256. Tile 8i x 128h, j-range 96.
// Mp[by][i][h] = max_{j in range} (B[j][h] + madd[i][j])
__global__ __launch_bounds__(256) void k_mm(const float* __restrict__ Bm,
    const unsigned char* __restrict__ mask, float* __restrict__ Mp)
{
    __shared__ float s_B[32][128];     // one 32-j chunk of B
    __shared__ float s_madd[96][8];    // 0 if edge else -1e30
    int t = threadIdx.x;
    int i0 = blockIdx.x * 8;
    int j0 = blockIdx.y * 96;
    for (int idx = t; idx < 768; idx += 256) {
        int jj = idx >> 3, i = idx & 7;
        s_madd[jj][i] = mask[(i0 + i) * NK + j0 + jj] ? 0.f : -1e30f;
    }
    int p = t & 63, g = t >> 6;        // h-pair p (h=2p), i-pair group g (i=2g,2g+1)
    v2f M0 = {-1e30f, -1e30f}, M1 = {-1e30f, -1e30f};
    const float4* B4 = (const float4*)Bm;   // row stride 32 float4
    for (int c = 0; c < 3; ++c) {
        __syncthreads();               // protect s_B reuse
        #pragma unroll
        for (int k = 0; k < 4; ++k) {
            int idx = t + k * 256;
            ((float4*)s_B)[idx] = B4[(size_t)(j0 + c * 32) * 32 + idx];
        }
        __syncthreads();
        #pragma unroll 8
        for (int jj = 0; jj < 32; ++jj) {
            v2f b = *(const v2f*)&s_B[jj][2 * p];
            float m0 = s_madd[c * 32 + jj][2 * g];
            float m1 = s_madd[c * 32 + jj][2 * g + 1];
            M0 = __builtin_elementwise_max(M0, b + (v2f){m0, m0});
            M1 = __builtin_elementwise_max(M1, b + (v2f){m1, m1});
        }
    }
    float* Mb = Mp + (size_t)blockIdx.y * NCF;
    *(v2f*)&Mb[(i0 + 2 * g) * 128 + 2 * p] = M0;
    *(v2f*)&Mb[(i0 + 2 * g + 1) * 128 + 2 * p] = M1;
}

// K5: combine 8 partials -> cf1 + GEMM Wne1 -> A1,B1. grid 384 x 512, i-tile 2.
__global__ __launch_bounds__(512) void k_cmb1(const float* __restrict__ Mp,
    const float* __restrict__ A0, const float* __restrict__ bne,
    const float* __restrict__ cf0, const unsigned int* __restrict__ flag,
    float* __restrict__ cf1, const float* __restrict__ Wne1,
    float* __restrict__ A1, float* __restrict__ B1)
{
    __shared__ float s_cf[2][128];
    int t = threadIdx.x;
    int k0 = blockIdx.x * 2;
    unsigned int fl = *flag;
    if (t < 256) {
        int kk = t >> 7, hh = t & 127;
        int g = (k0 + kk) * 128 + hh;
        float M = Mp[g];
        #pragma unroll
        for (int q = 1; q < 8; ++q) M = fmaxf(M, Mp[q * NCF + g]);
        float v = fl ? fmaxf(A0[g] + bne[hh] + M, 0.f) : cf0[g];
        s_cf[kk][hh] = v;
        cf1[g] = v;
    }
    __syncthreads();
    int h = t & 127, kk = (t >> 7) & 1, half = t >> 8;
    const float* W = Wne1 + half * 16384;
    const float* c = &s_cf[kk][0];
    float acc = 0.f;
    #pragma unroll 8
    for (int r = 0; r < 128; ++r)
        acc = fmaf(c[r], W[r * 128 + h], acc);
    float* D = half ? B1 : A1;
    D[(k0 + kk) * 128 + h] = acc;
}

// K7: combine 8 partials -> cf2 (local) + final heads. grid 384 x 512.
__global__ __launch_bounds__(512) void k_final(const float* __restrict__ cf0,
    const float* __restrict__ cf1, const float* __restrict__ Mp,
    const float* __restrict__ A1, const float* __restrict__ bne1,
    const unsigned int* __restrict__ flag,
    const float* __restrict__ Wc, const float* __restrict__ bc,
    const float* __restrict__ Wsem, const float* __restrict__ bsem,
    const float* __restrict__ W2, const float* __restrict__ b2,
    float* __restrict__ out)
{
    __shared__ float s_f[2][384];
    __shared__ float s_h[2][128];
    __shared__ float s_hp[2][128];
    int t = threadIdx.x;
    int k0 = blockIdx.x * 2;
    unsigned int fl = *flag;
    for (int idx = t; idx < 768; idx += 512) {
        int kk = idx >= 384 ? 1 : 0;
        int c = idx - kk * 384;
        int row = k0 + kk;
        float v;
        if (c < 128) v = cf0[row * 128 + c];
        else if (c < 256) v = cf1[row * 128 + (c - 128)];
        else {
            int hh = c - 256, g = row * 128 + hh;
            float M = Mp[g];
            #pragma unroll
            for (int q = 1; q < 8; ++q) M = fmaxf(M, Mp[q * NCF + g]);
            v = fl ? fmaxf(A1[g] + bne1[hh] + M, 0.f) : cf1[g];
        }
        s_f[kk][c] = v;
    }
    __syncthreads();
    int h = t & 127, rh = (t >> 7) & 1, kg = t >> 8;
    float acc = 0.f;
    {
        const float* f = &s_f[kg][rh * 192];
        const float* Wcp = Wc + rh * 192 * 128;
        #pragma unroll 8
        for (int r = 0; r < 192; ++r)
            acc = fmaf(f[r], Wcp[r * 128 + h], acc);
    }
    if (rh) s_hp[kg][h] = acc;
    __syncthreads();
    if (!rh) s_h[kg][h] = fmaxf(acc + s_hp[kg][h] + bc[h], 0.f);
    __syncthreads();
    float a2 = 0.f;
    {
        const float* hr = &s_h[kg][rh * 64];
        const float* W2p = W2 + rh * 64 * 128;
        #pragma unroll 8
        for (int r = 0; r < 64; ++r)
            a2 = fmaf(hr[r], W2p[r * 128 + h], a2);
    }
    if (rh) s_hp[kg][h] = a2;
    __syncthreads();
    if (!rh) out[(size_t)(k0 + kg) * 128 + h] = fmaxf(a2 + s_hp[kg][h] + b2[h], 0.f);
    if (t < 114) {
        int kk = t / 57, sidx = t - kk * 57;
        float ss = bsem[sidx];
        const float* hr = &s_h[kk][0];
        #pragma unroll 8
        for (int r = 0; r < 128; ++r)
            ss = fmaf(hr[r], Wsem[r * 57 + sidx], ss);
        out[98304 + (size_t)(k0 + kk) * 57 + sidx] = ss;
    }
}

extern "C" void kernel_launch(void* const* d_in, const int* in_sizes, int n_in,
                              void* d_out, int out_size, void* d_ws, size_t ws_size,
                              hipStream_t stream) {
    const float* pf   = (const float*)d_in[0];
    const float* Wp   = (const float*)d_in[1];
    const float* bp   = (const float*)d_in[2];
    const float* Wexi = (const float*)d_in[3];
    const float* bexi = (const float*)d_in[4];
    const float* Wel  = (const float*)d_in[5];
    const float* bel  = (const float*)d_in[6];
    const float* Wee  = (const float*)d_in[7];
    const float* bee  = (const float*)d_in[8];
    const float* Wne  = (const float*)d_in[9];
    const float* bne  = (const float*)d_in[10];
    const float* Wc   = (const float*)d_in[11];
    const float* bc   = (const float*)d_in[12];
    const float* Wsem = (const float*)d_in[13];
    const float* bsem = (const float*)d_in[14];
    const float* W2   = (const float*)d_in[15];
    const float* b2   = (const float*)d_in[16];
    float* out = (float*)d_out;
    float* ws  = (float*)d_ws;
    const int N = NCF;
    float* cf0 = ws;
    float* cf1 = ws + N;
    float* A   = ws + 2 * N;
    float* BT  = ws + 3 * N;
    float* A0  = ws + 4 * N;
    float* B0  = ws + 5 * N;
    float* A1  = ws + 6 * N;
    float* B1  = ws + 7 * N;
    float* Mp  = ws + 8 * N;                               // 8*N floats
    unsigned char* mask = (unsigned char*)(ws + 16 * N);   // 589824 bytes
    unsigned int* flag  = (unsigned int*)(mask + 589824);

    float* out_ex   = out + 142080;
    float* out_edge = out + 142848;

    k_parent<<<768, 256, 0, stream>>>(pf, Wp, bp, Wexi, bexi, cf0, out_ex, flag);
    k_dualmm<<<dim3(192, 2), 512, 0, stream>>>(cf0, Wel, A, BT, Wne, A0, B0);
    k_edge<<<dim3(192, 3), 256, 0, stream>>>(A, BT, bel, Wee, bee, out_ex, out_edge, mask, flag);
    k_mm<<<dim3(96, 8), 256, 0, stream>>>(B0, mask, Mp);
    k_cmb1<<<384, 512, 0, stream>>>(Mp, A0, bne, cf0, flag, cf1, Wne + 32768, A1, B1);
    k_mm<<<dim3(96, 8), 256, 0, stream>>>(B1, mask, Mp);
    k_final<<<384, 512, 0, stream>>>(cf0, cf1, Mp, A1, bne + 128, flag,
                                     Wc, bc, Wsem, bsem, W2, b2, out);
}